// Round 4
// baseline (578.878 us; speedup 1.0000x reference)
//
#include <hip/hip_runtime.h>
#include <stdint.h>

// BitStackLinear. Inputs x,u,vt are FLOAT32 on device (harness upcasts the
// reference's jnp.float16); qweight is int32; out is float32.
//   w[o,i] = sum_bit sign[bit,o,i] * (u[bit] @ vt[bit])[o,i]   (built as bf16 in d_ws)
//   out    = x @ w.T                                            (MFMA bf16 GEMM, f32 out)

#define W_BITS 4
#define OUT_F  4096
#define IN_F   4096
#define K_RANK 16
#define M_TOT  8192
#define QW_PER_BIT (OUT_F * IN_F / 8)

typedef __attribute__((ext_vector_type(8))) short bf16x8;
typedef __attribute__((ext_vector_type(4))) float f32x4;

__device__ __forceinline__ unsigned short f2bf(float f) {
  union { float f; unsigned int u; } c; c.f = f;
  unsigned int r = c.u + 0x7fffu + ((c.u >> 16) & 1u);  // RNE
  return (unsigned short)(r >> 16);
}

// ---------------------------------------------------------------------------
// Kernel 1: w[o][i] = sum_bit sign * (sum_k u[bit,o,k]*vt[bit,k,i]); w is bf16.
// Thread: 4 consecutive o x 8 consecutive i.
// ---------------------------------------------------------------------------
#define TO 4

__global__ __launch_bounds__(256) void build_w(
    const int*   __restrict__ qw,
    const float* __restrict__ u,    // [W_BITS][OUT_F][K_RANK] f32
    const float* __restrict__ vt,   // [W_BITS][K_RANK][IN_F] f32
    unsigned short* __restrict__ w) // [OUT_F][IN_F] bf16
{
  const int tid = blockIdx.x * 256 + threadIdx.x;
  const int ig  = tid & 511;            // i-group (8 i's)
  const int i0  = ig << 3;
  const int ob  = (tid >> 9) << 2;      // first of 4 o's

  float acc[TO][8];
  #pragma unroll
  for (int t = 0; t < TO; ++t)
    #pragma unroll
    for (int ii = 0; ii < 8; ++ii) acc[t][ii] = 0.0f;

  #pragma unroll
  for (int bit = 0; bit < W_BITS; ++bit) {
    float lr[TO][8];
    #pragma unroll
    for (int t = 0; t < TO; ++t)
      #pragma unroll
      for (int ii = 0; ii < 8; ++ii) lr[t][ii] = 0.0f;

    const float* vbase = vt + (size_t)(bit * K_RANK) * IN_F + i0;
    const float* ubase = u + (size_t)(bit * OUT_F + ob) * K_RANK;

    #pragma unroll
    for (int k = 0; k < K_RANK; ++k) {
      const f32x4 v0 = *reinterpret_cast<const f32x4*>(vbase + (size_t)k * IN_F);
      const f32x4 v1 = *reinterpret_cast<const f32x4*>(vbase + (size_t)k * IN_F + 4);
      float vf[8] = {v0[0], v0[1], v0[2], v0[3], v1[0], v1[1], v1[2], v1[3]};
      #pragma unroll
      for (int t = 0; t < TO; ++t) {
        const float uk = ubase[t * K_RANK + k];
        #pragma unroll
        for (int ii = 0; ii < 8; ++ii) lr[t][ii] += uk * vf[ii];
      }
    }

    #pragma unroll
    for (int t = 0; t < TO; ++t) {
      const int q = qw[(size_t)bit * QW_PER_BIT + (size_t)(ob + t) * (IN_F / 8) + ig];
      #pragma unroll
      for (int ii = 0; ii < 8; ++ii)
        acc[t][ii] += ((q >> ii) & 1) ? lr[t][ii] : -lr[t][ii];
    }
  }

  #pragma unroll
  for (int t = 0; t < TO; ++t) {
    unsigned short o8[8];
    #pragma unroll
    for (int ii = 0; ii < 8; ++ii) o8[ii] = f2bf(acc[t][ii]);
    *reinterpret_cast<uint4*>(w + (size_t)(ob + t) * IN_F + i0) =
        *reinterpret_cast<const uint4*>(o8);
  }
}

// ---------------------------------------------------------------------------
// Kernel 2: out[m][n] = sum_k X[m][k] * W[n][k]; X f32 (converted in staging),
// W bf16, out f32. 128x128 tile, BK=32, 4 waves (2x2), 4x4 mfma_16x16x32.
// ---------------------------------------------------------------------------
#define BM 128
#define BN 128
#define BK 32

__device__ __forceinline__ uint4 cvt8(f32x4 a, f32x4 b) {
  unsigned short o8[8] = {f2bf(a[0]), f2bf(a[1]), f2bf(a[2]), f2bf(a[3]),
                          f2bf(b[0]), f2bf(b[1]), f2bf(b[2]), f2bf(b[3])};
  return *reinterpret_cast<const uint4*>(o8);
}

__global__ __launch_bounds__(256) void gemm_bt(
    const float* __restrict__ X,             // [M_TOT][IN_F] f32
    const unsigned short* __restrict__ W,    // [OUT_F][IN_F] bf16
    float* __restrict__ out)                 // [M_TOT][OUT_F] f32
{
  __shared__ __align__(16) unsigned short As[BM * BK];   // [128][32] bf16
  __shared__ __align__(16) unsigned short Bs[BN * BK];

  const int nbn = OUT_F / BN;                      // 32
  const int cpx = (M_TOT / BM) * nbn / 8;          // 256 (2048 blocks, %8==0)
  const int bid = blockIdx.x;
  const int swz = (bid & 7) * cpx + (bid >> 3);    // XCD-bijective
  const int bm = swz / nbn;
  const int bn = swz % nbn;

  const int tid  = threadIdx.x;
  const int lane = tid & 63;
  const int wid  = tid >> 6;
  const int wm   = wid >> 1;
  const int wn   = wid & 1;

  const int srow = tid >> 2;           // 0..63
  const int scol = (tid & 3) << 3;     // 0,8,16,24

  const float*          Ag = X + (size_t)(bm * BM + srow) * IN_F + scol;
  const unsigned short* Bg = W + (size_t)(bn * BN + srow) * IN_F + scol;

  const int fr = lane & 15;
  const int fk = (lane >> 4) << 3;

  f32x4 acc[4][4];
  #pragma unroll
  for (int m = 0; m < 4; ++m)
    #pragma unroll
    for (int n = 0; n < 4; ++n)
      acc[m][n] = (f32x4){0.f, 0.f, 0.f, 0.f};

  for (int k0 = 0; k0 < IN_F; k0 += BK) {
    const f32x4 a0a = *reinterpret_cast<const f32x4*>(Ag + k0);
    const f32x4 a0b = *reinterpret_cast<const f32x4*>(Ag + k0 + 4);
    const f32x4 a1a = *reinterpret_cast<const f32x4*>(Ag + (size_t)64 * IN_F + k0);
    const f32x4 a1b = *reinterpret_cast<const f32x4*>(Ag + (size_t)64 * IN_F + k0 + 4);
    const uint4 b0  = *reinterpret_cast<const uint4*>(Bg + k0);
    const uint4 b1  = *reinterpret_cast<const uint4*>(Bg + (size_t)64 * IN_F + k0);

    __syncthreads();   // prior iteration's LDS reads complete before overwrite
    *reinterpret_cast<uint4*>(As + tid * 8)        = cvt8(a0a, a0b);
    *reinterpret_cast<uint4*>(As + 2048 + tid * 8) = cvt8(a1a, a1b);
    *reinterpret_cast<uint4*>(Bs + tid * 8)        = b0;
    *reinterpret_cast<uint4*>(Bs + 2048 + tid * 8) = b1;
    __syncthreads();

    bf16x8 af[4], bfv[4];
    #pragma unroll
    for (int m = 0; m < 4; ++m)
      af[m] = *reinterpret_cast<const bf16x8*>(&As[(wm * 64 + m * 16 + fr) * BK + fk]);
    #pragma unroll
    for (int n = 0; n < 4; ++n)
      bfv[n] = *reinterpret_cast<const bf16x8*>(&Bs[(wn * 64 + n * 16 + fr) * BK + fk]);

    #pragma unroll
    for (int m = 0; m < 4; ++m)
      #pragma unroll
      for (int n = 0; n < 4; ++n)
        acc[m][n] = __builtin_amdgcn_mfma_f32_16x16x32_bf16(af[m], bfv[n], acc[m][n], 0, 0, 0);
  }

  // epilogue: D mapping col = lane&15, row = (lane>>4)*4 + j   [m89 verified]
  const int rsub = (lane >> 4) << 2;
  #pragma unroll
  for (int m = 0; m < 4; ++m) {
    #pragma unroll
    for (int n = 0; n < 4; ++n) {
      const int col = bn * BN + wn * 64 + n * 16 + (lane & 15);
      #pragma unroll
      for (int j = 0; j < 4; ++j) {
        const int row = bm * BM + wm * 64 + m * 16 + rsub + j;
        out[(size_t)row * OUT_F + col] = acc[m][n][j];
      }
    }
  }
}

// ---------------------------------------------------------------------------
extern "C" void kernel_launch(void* const* d_in, const int* in_sizes, int n_in,
                              void* d_out, int out_size, void* d_ws, size_t ws_size,
                              hipStream_t stream) {
  (void)in_sizes; (void)n_in; (void)out_size; (void)ws_size;

  const float* x  = (const float*)d_in[0];  // f32 [4,2048,4096]
  const int*   qw = (const int*)d_in[1];    // [4, 2097152]
  const float* u  = (const float*)d_in[2];  // f32 [4,4096,16]
  const float* vt = (const float*)d_in[3];  // f32 [4,16,4096]
  float* out = (float*)d_out;               // f32 [4,2048,4096]
  unsigned short* w = (unsigned short*)d_ws; // bf16 [4096][4096] = 32MB scratch

  build_w<<<dim3(2048), dim3(256), 0, stream>>>(qw, u, vt, w);
  gemm_bt<<<dim3(2048), dim3(256), 0, stream>>>(x, w, out);
}

// Round 5
// 519.503 us; speedup vs baseline: 1.1143x; 1.1143x over previous
//
#include <hip/hip_runtime.h>
#include <stdint.h>

// BitStackLinear. Device dtypes: x,u,vt = float32 (harness upcasts fp16),
// qweight = int32, out = float32.
// Pipeline: build_w (w bf16 in ws) ; convert_x (x bf16 in ws) ; m97-style
// bf16 GEMM with global_load_lds staging. Fallback to reg-staged GEMM if
// ws_size can't hold both scratch buffers.

#define W_BITS 4
#define OUT_F  4096
#define IN_F   4096
#define K_RANK 16
#define M_TOT  8192
#define QW_PER_BIT (OUT_F * IN_F / 8)

typedef __attribute__((ext_vector_type(8))) short bf16x8;
typedef __attribute__((ext_vector_type(4))) float f32x4;

__device__ __forceinline__ unsigned short f2bf(float f) {
  union { float f; unsigned int u; } c; c.f = f;
  unsigned int r = c.u + 0x7fffu + ((c.u >> 16) & 1u);  // RNE
  return (unsigned short)(r >> 16);
}

// ---------------------------------------------------------------------------
// Kernel 0: X f32 -> bf16 (vectorized, grid-stride). 33.55M elements.
// ---------------------------------------------------------------------------
__global__ __launch_bounds__(256) void convert_x(
    const float* __restrict__ X, unsigned short* __restrict__ Xb, int n8)
{
  const int stride = gridDim.x * blockDim.x;
  for (int i = blockIdx.x * blockDim.x + threadIdx.x; i < n8; i += stride) {
    const f32x4 a = *reinterpret_cast<const f32x4*>(X + (size_t)i * 8);
    const f32x4 b = *reinterpret_cast<const f32x4*>(X + (size_t)i * 8 + 4);
    unsigned short o8[8] = {f2bf(a[0]), f2bf(a[1]), f2bf(a[2]), f2bf(a[3]),
                            f2bf(b[0]), f2bf(b[1]), f2bf(b[2]), f2bf(b[3])};
    *reinterpret_cast<uint4*>(Xb + (size_t)i * 8) = *reinterpret_cast<const uint4*>(o8);
  }
}

// ---------------------------------------------------------------------------
// Kernel 1: w[o][i] = sum_bit sign * (sum_k u[bit,o,k]*vt[bit,k,i]); w bf16.
// ---------------------------------------------------------------------------
#define TO 4

__global__ __launch_bounds__(256) void build_w(
    const int*   __restrict__ qw,
    const float* __restrict__ u,    // [W_BITS][OUT_F][K_RANK]
    const float* __restrict__ vt,   // [W_BITS][K_RANK][IN_F]
    unsigned short* __restrict__ w) // [OUT_F][IN_F] bf16
{
  const int tid = blockIdx.x * 256 + threadIdx.x;
  const int ig  = tid & 511;
  const int i0  = ig << 3;
  const int ob  = (tid >> 9) << 2;

  float acc[TO][8];
  #pragma unroll
  for (int t = 0; t < TO; ++t)
    #pragma unroll
    for (int ii = 0; ii < 8; ++ii) acc[t][ii] = 0.0f;

  #pragma unroll
  for (int bit = 0; bit < W_BITS; ++bit) {
    float lr[TO][8];
    #pragma unroll
    for (int t = 0; t < TO; ++t)
      #pragma unroll
      for (int ii = 0; ii < 8; ++ii) lr[t][ii] = 0.0f;

    const float* vbase = vt + (size_t)(bit * K_RANK) * IN_F + i0;
    const float* ubase = u + (size_t)(bit * OUT_F + ob) * K_RANK;

    #pragma unroll
    for (int k = 0; k < K_RANK; ++k) {
      const f32x4 v0 = *reinterpret_cast<const f32x4*>(vbase + (size_t)k * IN_F);
      const f32x4 v1 = *reinterpret_cast<const f32x4*>(vbase + (size_t)k * IN_F + 4);
      float vf[8] = {v0[0], v0[1], v0[2], v0[3], v1[0], v1[1], v1[2], v1[3]};
      #pragma unroll
      for (int t = 0; t < TO; ++t) {
        const float uk = ubase[t * K_RANK + k];
        #pragma unroll
        for (int ii = 0; ii < 8; ++ii) lr[t][ii] += uk * vf[ii];
      }
    }

    #pragma unroll
    for (int t = 0; t < TO; ++t) {
      const int q = qw[(size_t)bit * QW_PER_BIT + (size_t)(ob + t) * (IN_F / 8) + ig];
      #pragma unroll
      for (int ii = 0; ii < 8; ++ii)
        acc[t][ii] += ((q >> ii) & 1) ? lr[t][ii] : -lr[t][ii];
    }
  }

  #pragma unroll
  for (int t = 0; t < TO; ++t) {
    unsigned short o8[8];
    #pragma unroll
    for (int ii = 0; ii < 8; ++ii) o8[ii] = f2bf(acc[t][ii]);
    *reinterpret_cast<uint4*>(w + (size_t)(ob + t) * IN_F + i0) =
        *reinterpret_cast<const uint4*>(o8);
  }
}

// ---------------------------------------------------------------------------
// Kernel 2 (main): pure bf16 NT GEMM, m97 structure: 128x128 tile, BK=32,
// 4 waves (2x2), 4x4 mfma_16x16x32, global_load_lds width-16, XCD swizzle.
// out is f32.
// ---------------------------------------------------------------------------
#define BM 128
#define BN 128
#define BK 32

__device__ __forceinline__ void gll16(unsigned short* lds, const unsigned short* g) {
  __builtin_amdgcn_global_load_lds(
      (const __attribute__((address_space(1))) unsigned int*)g,
      (__attribute__((address_space(3))) unsigned int*)lds,
      16, 0, 0);
}

__global__ __launch_bounds__(256) void gemm_bf16(
    const unsigned short* __restrict__ X,    // [M_TOT][IN_F] bf16
    const unsigned short* __restrict__ W,    // [OUT_F][IN_F] bf16
    float* __restrict__ out)                 // [M_TOT][OUT_F] f32
{
  __shared__ __align__(16) unsigned short As[BM * BK];
  __shared__ __align__(16) unsigned short Bs[BN * BK];

  const int nbn = OUT_F / BN;                      // 32
  const int cpx = (M_TOT / BM) * nbn / 8;          // 256
  const int bid = blockIdx.x;
  const int swz = (bid & 7) * cpx + (bid >> 3);    // XCD-bijective (2048%8==0)
  const int bm = swz / nbn;
  const int bn = swz % nbn;

  const int tid  = threadIdx.x;
  const int lane = tid & 63;
  const int wid  = tid >> 6;
  const int wm   = wid >> 1;
  const int wn   = wid & 1;

  const int srow = tid >> 2;           // 0..63
  const int scol = (tid & 3) << 3;     // 0,8,16,24

  const unsigned short* Ag = X + (size_t)(bm * BM + srow) * IN_F + scol;
  const unsigned short* Bg = W + (size_t)(bn * BN + srow) * IN_F + scol;

  const int fr = lane & 15;
  const int fk = (lane >> 4) << 3;

  f32x4 acc[4][4];
  #pragma unroll
  for (int m = 0; m < 4; ++m)
    #pragma unroll
    for (int n = 0; n < 4; ++n)
      acc[m][n] = (f32x4){0.f, 0.f, 0.f, 0.f};

  for (int k0 = 0; k0 < IN_F; k0 += BK) {
    gll16(As + tid * 8,        Ag + k0);
    gll16(As + 2048 + tid * 8, Ag + (size_t)64 * IN_F + k0);
    gll16(Bs + tid * 8,        Bg + k0);
    gll16(Bs + 2048 + tid * 8, Bg + (size_t)64 * IN_F + k0);
    __syncthreads();   // compiler drains vmcnt before s_barrier

    bf16x8 af[4], bfv[4];
    #pragma unroll
    for (int m = 0; m < 4; ++m)
      af[m] = *reinterpret_cast<const bf16x8*>(&As[(wm * 64 + m * 16 + fr) * BK + fk]);
    #pragma unroll
    for (int n = 0; n < 4; ++n)
      bfv[n] = *reinterpret_cast<const bf16x8*>(&Bs[(wn * 64 + n * 16 + fr) * BK + fk]);

    #pragma unroll
    for (int m = 0; m < 4; ++m)
      #pragma unroll
      for (int n = 0; n < 4; ++n)
        acc[m][n] = __builtin_amdgcn_mfma_f32_16x16x32_bf16(af[m], bfv[n], acc[m][n], 0, 0, 0);

    __syncthreads();
  }

  const int rsub = (lane >> 4) << 2;
  #pragma unroll
  for (int m = 0; m < 4; ++m) {
    #pragma unroll
    for (int n = 0; n < 4; ++n) {
      const int col = bn * BN + wn * 64 + n * 16 + (lane & 15);
      #pragma unroll
      for (int j = 0; j < 4; ++j) {
        const int row = bm * BM + wm * 64 + m * 16 + rsub + j;
        out[(size_t)row * OUT_F + col] = acc[m][n][j];
      }
    }
  }
}

// ---------------------------------------------------------------------------
// Fallback GEMM (round-4, passing): A f32 reg-staged+converted, W bf16.
// Used only if ws_size < 96MB.
// ---------------------------------------------------------------------------
__device__ __forceinline__ uint4 cvt8(f32x4 a, f32x4 b) {
  unsigned short o8[8] = {f2bf(a[0]), f2bf(a[1]), f2bf(a[2]), f2bf(a[3]),
                          f2bf(b[0]), f2bf(b[1]), f2bf(b[2]), f2bf(b[3])};
  return *reinterpret_cast<const uint4*>(o8);
}

__global__ __launch_bounds__(256) void gemm_f32stage(
    const float* __restrict__ X,
    const unsigned short* __restrict__ W,
    float* __restrict__ out)
{
  __shared__ __align__(16) unsigned short As[BM * BK];
  __shared__ __align__(16) unsigned short Bs[BN * BK];

  const int nbn = OUT_F / BN;
  const int cpx = (M_TOT / BM) * nbn / 8;
  const int bid = blockIdx.x;
  const int swz = (bid & 7) * cpx + (bid >> 3);
  const int bm = swz / nbn;
  const int bn = swz % nbn;

  const int tid  = threadIdx.x;
  const int lane = tid & 63;
  const int wid  = tid >> 6;
  const int wm   = wid >> 1;
  const int wn   = wid & 1;
  const int srow = tid >> 2;
  const int scol = (tid & 3) << 3;

  const float*          Ag = X + (size_t)(bm * BM + srow) * IN_F + scol;
  const unsigned short* Bg = W + (size_t)(bn * BN + srow) * IN_F + scol;

  const int fr = lane & 15;
  const int fk = (lane >> 4) << 3;

  f32x4 acc[4][4];
  #pragma unroll
  for (int m = 0; m < 4; ++m)
    #pragma unroll
    for (int n = 0; n < 4; ++n)
      acc[m][n] = (f32x4){0.f, 0.f, 0.f, 0.f};

  for (int k0 = 0; k0 < IN_F; k0 += BK) {
    const f32x4 a0a = *reinterpret_cast<const f32x4*>(Ag + k0);
    const f32x4 a0b = *reinterpret_cast<const f32x4*>(Ag + k0 + 4);
    const f32x4 a1a = *reinterpret_cast<const f32x4*>(Ag + (size_t)64 * IN_F + k0);
    const f32x4 a1b = *reinterpret_cast<const f32x4*>(Ag + (size_t)64 * IN_F + k0 + 4);
    const uint4 b0  = *reinterpret_cast<const uint4*>(Bg + k0);
    const uint4 b1  = *reinterpret_cast<const uint4*>(Bg + (size_t)64 * IN_F + k0);

    __syncthreads();
    *reinterpret_cast<uint4*>(As + tid * 8)        = cvt8(a0a, a0b);
    *reinterpret_cast<uint4*>(As + 2048 + tid * 8) = cvt8(a1a, a1b);
    *reinterpret_cast<uint4*>(Bs + tid * 8)        = b0;
    *reinterpret_cast<uint4*>(Bs + 2048 + tid * 8) = b1;
    __syncthreads();

    bf16x8 af[4], bfv[4];
    #pragma unroll
    for (int m = 0; m < 4; ++m)
      af[m] = *reinterpret_cast<const bf16x8*>(&As[(wm * 64 + m * 16 + fr) * BK + fk]);
    #pragma unroll
    for (int n = 0; n < 4; ++n)
      bfv[n] = *reinterpret_cast<const bf16x8*>(&Bs[(wn * 64 + n * 16 + fr) * BK + fk]);

    #pragma unroll
    for (int m = 0; m < 4; ++m)
      #pragma unroll
      for (int n = 0; n < 4; ++n)
        acc[m][n] = __builtin_amdgcn_mfma_f32_16x16x32_bf16(af[m], bfv[n], acc[m][n], 0, 0, 0);
  }

  const int rsub = (lane >> 4) << 2;
  #pragma unroll
  for (int m = 0; m < 4; ++m) {
    #pragma unroll
    for (int n = 0; n < 4; ++n) {
      const int col = bn * BN + wn * 64 + n * 16 + (lane & 15);
      #pragma unroll
      for (int j = 0; j < 4; ++j) {
        const int row = bm * BM + wm * 64 + m * 16 + rsub + j;
        out[(size_t)row * OUT_F + col] = acc[m][n][j];
      }
    }
  }
}

// ---------------------------------------------------------------------------
extern "C" void kernel_launch(void* const* d_in, const int* in_sizes, int n_in,
                              void* d_out, int out_size, void* d_ws, size_t ws_size,
                              hipStream_t stream) {
  (void)in_sizes; (void)n_in; (void)out_size;

  const float* x  = (const float*)d_in[0];
  const int*   qw = (const int*)d_in[1];
  const float* u  = (const float*)d_in[2];
  const float* vt = (const float*)d_in[3];
  float* out = (float*)d_out;

  unsigned short* w = (unsigned short*)d_ws;                   // 32 MB
  const size_t W_BYTES  = (size_t)OUT_F * IN_F * 2;            // 33554432
  const size_t XB_BYTES = (size_t)M_TOT * IN_F * 2;            // 67108864

  build_w<<<dim3(2048), dim3(256), 0, stream>>>(qw, u, vt, w);

  if (ws_size >= W_BYTES + XB_BYTES) {
    unsigned short* xb = w + (size_t)OUT_F * IN_F;
    convert_x<<<dim3(2048), dim3(256), 0, stream>>>(x, xb, M_TOT * IN_F / 8);
    gemm_bf16<<<dim3(2048), dim3(256), 0, stream>>>(xb, w, out);
  } else {
    gemm_f32stage<<<dim3(2048), dim3(256), 0, stream>>>(x, w, out);
  }
}

// Round 6
// 511.868 us; speedup vs baseline: 1.1309x; 1.0149x over previous
//
#include <hip/hip_runtime.h>
#include <stdint.h>

// BitStackLinear. Device dtypes: x,u,vt = float32 (harness upcasts fp16),
// qweight = int32, out = float32.
// Pipeline: build_w (w bf16) ; convert_x (x bf16) ; 256x256 8-phase bf16 GEMM
// (T3+T4 counted vmcnt + T5 setprio, linear LDS this round; T2 swizzle next).

#define W_BITS 4
#define OUT_F  4096
#define IN_F   4096
#define K_RANK 16
#define M_TOT  8192
#define QW_PER_BIT (OUT_F * IN_F / 8)

typedef __attribute__((ext_vector_type(8))) short bf16x8;
typedef __attribute__((ext_vector_type(4))) float f32x4;

__device__ __forceinline__ unsigned short f2bf(float f) {
  union { float f; unsigned int u; } c; c.f = f;
  unsigned int r = c.u + 0x7fffu + ((c.u >> 16) & 1u);  // RNE
  return (unsigned short)(r >> 16);
}

// ---------------------------------------------------------------------------
// Kernel 0: X f32 -> bf16
// ---------------------------------------------------------------------------
__global__ __launch_bounds__(256) void convert_x(
    const float* __restrict__ X, unsigned short* __restrict__ Xb, int n8)
{
  const int stride = gridDim.x * blockDim.x;
  for (int i = blockIdx.x * blockDim.x + threadIdx.x; i < n8; i += stride) {
    const f32x4 a = *reinterpret_cast<const f32x4*>(X + (size_t)i * 8);
    const f32x4 b = *reinterpret_cast<const f32x4*>(X + (size_t)i * 8 + 4);
    unsigned short o8[8] = {f2bf(a[0]), f2bf(a[1]), f2bf(a[2]), f2bf(a[3]),
                            f2bf(b[0]), f2bf(b[1]), f2bf(b[2]), f2bf(b[3])};
    *reinterpret_cast<uint4*>(Xb + (size_t)i * 8) = *reinterpret_cast<const uint4*>(o8);
  }
}

// ---------------------------------------------------------------------------
// Kernel 1: w[o][i] = sum_bit sign * (u[bit] @ vt[bit])[o][i]; w bf16.
// ---------------------------------------------------------------------------
#define TO 4

__global__ __launch_bounds__(256) void build_w(
    const int*   __restrict__ qw,
    const float* __restrict__ u,
    const float* __restrict__ vt,
    unsigned short* __restrict__ w)
{
  const int tid = blockIdx.x * 256 + threadIdx.x;
  const int ig  = tid & 511;
  const int i0  = ig << 3;
  const int ob  = (tid >> 9) << 2;

  float acc[TO][8];
  #pragma unroll
  for (int t = 0; t < TO; ++t)
    #pragma unroll
    for (int ii = 0; ii < 8; ++ii) acc[t][ii] = 0.0f;

  #pragma unroll
  for (int bit = 0; bit < W_BITS; ++bit) {
    float lr[TO][8];
    #pragma unroll
    for (int t = 0; t < TO; ++t)
      #pragma unroll
      for (int ii = 0; ii < 8; ++ii) lr[t][ii] = 0.0f;

    const float* vbase = vt + (size_t)(bit * K_RANK) * IN_F + i0;
    const float* ubase = u + (size_t)(bit * OUT_F + ob) * K_RANK;

    #pragma unroll
    for (int k = 0; k < K_RANK; ++k) {
      const f32x4 v0 = *reinterpret_cast<const f32x4*>(vbase + (size_t)k * IN_F);
      const f32x4 v1 = *reinterpret_cast<const f32x4*>(vbase + (size_t)k * IN_F + 4);
      float vf[8] = {v0[0], v0[1], v0[2], v0[3], v1[0], v1[1], v1[2], v1[3]};
      #pragma unroll
      for (int t = 0; t < TO; ++t) {
        const float uk = ubase[t * K_RANK + k];
        #pragma unroll
        for (int ii = 0; ii < 8; ++ii) lr[t][ii] += uk * vf[ii];
      }
    }

    #pragma unroll
    for (int t = 0; t < TO; ++t) {
      const int q = qw[(size_t)bit * QW_PER_BIT + (size_t)(ob + t) * (IN_F / 8) + ig];
      #pragma unroll
      for (int ii = 0; ii < 8; ++ii)
        acc[t][ii] += ((q >> ii) & 1) ? lr[t][ii] : -lr[t][ii];
    }
  }

  #pragma unroll
  for (int t = 0; t < TO; ++t) {
    unsigned short o8[8];
    #pragma unroll
    for (int ii = 0; ii < 8; ++ii) o8[ii] = f2bf(acc[t][ii]);
    *reinterpret_cast<uint4*>(w + (size_t)(ob + t) * IN_F + i0) =
        *reinterpret_cast<const uint4*>(o8);
  }
}

// ---------------------------------------------------------------------------
// Kernel 2 (main): 256x256 tile, BK=64, 512 thr = 8 waves (2Mx4N), 8-phase
// schedule with counted vmcnt(4), raw barriers, setprio. Linear LDS.
// Wave fragment interleave: m-block = f*2+wm (f=0..7), n-block = g*4+wn
// (g=0..3) so quadrant (mh,nh) touches exactly A-half mh / B-half nh.
// ---------------------------------------------------------------------------
__device__ __forceinline__ void gll16(unsigned short* lds, const unsigned short* g) {
  __builtin_amdgcn_global_load_lds(
      (const __attribute__((address_space(1))) unsigned int*)g,
      (__attribute__((address_space(3))) unsigned int*)lds,
      16, 0, 0);
}

__global__ __launch_bounds__(512, 2) void gemm_256(
    const unsigned short* __restrict__ X,    // [M_TOT][IN_F] bf16
    const unsigned short* __restrict__ W,    // [OUT_F][IN_F] bf16
    float* __restrict__ out)                 // [M_TOT][OUT_F] f32
{
  __shared__ __align__(16) unsigned short Al[2][256][64];   // 64 KiB
  __shared__ __align__(16) unsigned short Bl[2][256][64];   // 64 KiB

  const int bid = blockIdx.x;                 // 512 blocks (32 x 16)
  const int swz = (bid & 7) * 64 + (bid >> 3);  // XCD-bijective (512%8==0)
  const int bm = swz >> 4;                    // 0..31
  const int bn = swz & 15;                    // 0..15

  const int tid  = threadIdx.x;
  const int lane = tid & 63;
  const int wid  = tid >> 6;     // 0..7
  const int wm   = wid >> 2;     // 0..1
  const int wn   = wid & 3;      // 0..3

  // staging: thread covers 16B; half-tile (128x64) = 2 issues/thread
  const int sr = tid >> 3;            // 0..63
  const int sc = (tid & 7) << 3;      // 0..56 shorts

  const unsigned short* Abase = X + (size_t)(bm * 256 + sr) * IN_F + sc;
  const unsigned short* Bbase = W + (size_t)(bn * 256 + sr) * IN_F + sc;
  unsigned short* Alt = &Al[0][0][0] + tid * 8;   // + buf*16384 + (h&1)*8192 + j*4096
  unsigned short* Blt = &Bl[0][0][0] + tid * 8;

  // fragment read coords (mfma_f32_16x16x32_bf16: lane l -> row l&15, k=(l>>4)*8..+7)
  const int fr = lane & 15;
  const int fk = (lane >> 4) << 3;
  const int aRow = (wm * 16 + fr) * 64 + fk;   // + f*2048 + ks*32 + cbase
  const int bRow = (wn * 16 + fr) * 64 + fk;   // + g*4096 + ks*32 + cbase
  const unsigned short* Ar = &Al[0][0][0];
  const unsigned short* Br = &Bl[0][0][0];

  f32x4 acc[8][4];
  #pragma unroll
  for (int f = 0; f < 8; ++f)
    #pragma unroll
    for (int g = 0; g < 4; ++g)
      acc[f][g] = (f32x4){0.f, 0.f, 0.f, 0.f};

  // half-tile h: 0 = A rows 0-127, 1 = A rows 128-255, 2 = B-h0, 3 = B-h1
#define STAGE(buf, h, tn_) do {                                                        \
    const unsigned short* gs_ = ((h) < 2 ? Abase : Bbase)                              \
        + (size_t)(((h) & 1) * 128) * IN_F + (size_t)(tn_) * 64;                       \
    unsigned short* ld_ = ((h) < 2 ? Alt : Blt) + (buf) * 16384 + ((h) & 1) * 8192;    \
    gll16(ld_, gs_);                                                                   \
    gll16(ld_ + 4096, gs_ + (size_t)64 * IN_F);                                        \
  } while (0)

  // counted wait + collective guarantee point; sched_barrier pins illegal hoists
#define WAITBAR() do {                                                                 \
    asm volatile("s_waitcnt vmcnt(4)" ::: "memory");                                   \
    __builtin_amdgcn_s_barrier();                                                      \
    __builtin_amdgcn_sched_barrier(0);                                                 \
  } while (0)

#define PH_READ_A(mh_) {                                                               \
    _Pragma("unroll") for (int f = 0; f < 4; ++f)                                      \
      _Pragma("unroll") for (int ks = 0; ks < 2; ++ks)                                 \
        aF[f][ks] = *reinterpret_cast<const bf16x8*>(                                  \
            Ar + cbase + ((mh_) * 4 + f) * 2048 + ks * 32 + aRow); }

#define PH_READ_B(nh_) {                                                               \
    _Pragma("unroll") for (int g = 0; g < 2; ++g)                                      \
      _Pragma("unroll") for (int ks = 0; ks < 2; ++ks)                                 \
        bF[g][ks] = *reinterpret_cast<const bf16x8*>(                                  \
            Br + cbase + ((nh_) * 2 + g) * 4096 + ks * 32 + bRow); }

#define PH_MFMA(mh_, nh_) do {                                                         \
    __builtin_amdgcn_s_setprio(1);                                                     \
    _Pragma("unroll") for (int f = 0; f < 4; ++f)                                      \
      _Pragma("unroll") for (int g = 0; g < 2; ++g)                                    \
        _Pragma("unroll") for (int ks = 0; ks < 2; ++ks)                               \
          acc[(mh_) * 4 + f][(nh_) * 2 + g] = __builtin_amdgcn_mfma_f32_16x16x32_bf16( \
              aF[f][ks], bF[g][ks], acc[(mh_) * 4 + f][(nh_) * 2 + g], 0, 0, 0);       \
    __builtin_amdgcn_s_setprio(0);                                                     \
  } while (0)

  // prologue: stage tile 0 (order A-h0, B-h0, A-h1, B-h1), vmcnt(4) -> first
  // two halves landed; steady-state invariant established.
  STAGE(0, 0, 0);
  STAGE(0, 2, 0);
  STAGE(0, 1, 0);
  STAGE(0, 3, 0);
  asm volatile("s_waitcnt vmcnt(4)" ::: "memory");
  __builtin_amdgcn_s_barrier();
  __builtin_amdgcn_sched_barrier(0);

  bf16x8 aF[4][2], bF[2][2];

  #pragma unroll 2
  for (int T = 0; T < 64; ++T) {
    const int cc = T & 1, oo = cc ^ 1;
    const int tn = (T < 63) ? T + 1 : 63;   // clamped prefetch (dup of 63, unread)
    const int cbase = cc * 16384;

    // phase 1: quadrant (0,0) — needs A-h0,B-h0 (landed 2 stage-groups ago)
    PH_READ_A(0); PH_READ_B(0);
    STAGE(oo, 0, tn);                 // next A-h0
    WAITBAR();
    PH_MFMA(0, 0);
    __builtin_amdgcn_s_barrier();

    // phase 2: quadrant (1,0) — needs A-h1 (completed by phase-1 vmcnt(4))
    PH_READ_A(1);
    STAGE(oo, 2, tn);                 // next B-h0
    WAITBAR();
    PH_MFMA(1, 0);
    __builtin_amdgcn_s_barrier();

    // phase 3: quadrant (1,1) — needs B-h1 (completed by phase-2 vmcnt(4))
    PH_READ_B(1);
    STAGE(oo, 1, tn);                 // next A-h1
    WAITBAR();
    PH_MFMA(1, 1);
    __builtin_amdgcn_s_barrier();

    // phase 4: quadrant (0,1) — re-reads A-h0 (long landed)
    PH_READ_A(0);
    STAGE(oo, 3, tn);                 // next B-h1
    WAITBAR();
    PH_MFMA(0, 1);
    __builtin_amdgcn_s_barrier();
  }

  asm volatile("s_waitcnt vmcnt(0)" ::: "memory");

  // epilogue: D mapping col = lane&15, row = (lane>>4)*4 + j [m89]
  const int rsub = (lane >> 4) << 2;
  #pragma unroll
  for (int f = 0; f < 8; ++f) {
    const int row = bm * 256 + (f * 2 + wm) * 16 + rsub;
    #pragma unroll
    for (int g = 0; g < 4; ++g) {
      const int col = bn * 256 + (g * 4 + wn) * 16 + (lane & 15);
      float* op = out + (size_t)row * OUT_F + col;
      #pragma unroll
      for (int j = 0; j < 4; ++j) op[(size_t)j * OUT_F] = acc[f][g][j];
    }
  }
#undef STAGE
#undef WAITBAR
#undef PH_READ_A
#undef PH_READ_B
#undef PH_MFMA
}

// ---------------------------------------------------------------------------
// Fallback GEMM (round-4, passing): A f32 reg-staged+converted. ws < 96MB only.
// ---------------------------------------------------------------------------
#define BM 128
#define BN 128
#define BK 32

__device__ __forceinline__ uint4 cvt8(f32x4 a, f32x4 b) {
  unsigned short o8[8] = {f2bf(a[0]), f2bf(a[1]), f2bf(a[2]), f2bf(a[3]),
                          f2bf(b[0]), f2bf(b[1]), f2bf(b[2]), f2bf(b[3])};
  return *reinterpret_cast<const uint4*>(o8);
}

__global__ __launch_bounds__(256) void gemm_f32stage(
    const float* __restrict__ X,
    const unsigned short* __restrict__ W,
    float* __restrict__ out)
{
  __shared__ __align__(16) unsigned short As[BM * BK];
  __shared__ __align__(16) unsigned short Bs[BN * BK];

  const int nbn = OUT_F / BN;
  const int cpx = (M_TOT / BM) * nbn / 8;
  const int bid = blockIdx.x;
  const int swz = (bid & 7) * cpx + (bid >> 3);
  const int bm = swz / nbn;
  const int bn = swz % nbn;

  const int tid  = threadIdx.x;
  const int lane = tid & 63;
  const int wid  = tid >> 6;
  const int wm   = wid >> 1;
  const int wn   = wid & 1;
  const int srow = tid >> 2;
  const int scol = (tid & 3) << 3;

  const float*          Ag = X + (size_t)(bm * BM + srow) * IN_F + scol;
  const unsigned short* Bg = W + (size_t)(bn * BN + srow) * IN_F + scol;

  const int fr = lane & 15;
  const int fk = (lane >> 4) << 3;

  f32x4 acc[4][4];
  #pragma unroll
  for (int m = 0; m < 4; ++m)
    #pragma unroll
    for (int n = 0; n < 4; ++n)
      acc[m][n] = (f32x4){0.f, 0.f, 0.f, 0.f};

  for (int k0 = 0; k0 < IN_F; k0 += BK) {
    const f32x4 a0a = *reinterpret_cast<const f32x4*>(Ag + k0);
    const f32x4 a0b = *reinterpret_cast<const f32x4*>(Ag + k0 + 4);
    const f32x4 a1a = *reinterpret_cast<const f32x4*>(Ag + (size_t)64 * IN_F + k0);
    const f32x4 a1b = *reinterpret_cast<const f32x4*>(Ag + (size_t)64 * IN_F + k0 + 4);
    const uint4 b0  = *reinterpret_cast<const uint4*>(Bg + k0);
    const uint4 b1  = *reinterpret_cast<const uint4*>(Bg + (size_t)64 * IN_F + k0);

    __syncthreads();
    *reinterpret_cast<uint4*>(As + tid * 8)        = cvt8(a0a, a0b);
    *reinterpret_cast<uint4*>(As + 2048 + tid * 8) = cvt8(a1a, a1b);
    *reinterpret_cast<uint4*>(Bs + tid * 8)        = b0;
    *reinterpret_cast<uint4*>(Bs + 2048 + tid * 8) = b1;
    __syncthreads();

    bf16x8 af[4], bfv[4];
    #pragma unroll
    for (int m = 0; m < 4; ++m)
      af[m] = *reinterpret_cast<const bf16x8*>(&As[(wm * 64 + m * 16 + fr) * BK + fk]);
    #pragma unroll
    for (int n = 0; n < 4; ++n)
      bfv[n] = *reinterpret_cast<const bf16x8*>(&Bs[(wn * 64 + n * 16 + fr) * BK + fk]);

    #pragma unroll
    for (int m = 0; m < 4; ++m)
      #pragma unroll
      for (int n = 0; n < 4; ++n)
        acc[m][n] = __builtin_amdgcn_mfma_f32_16x16x32_bf16(af[m], bfv[n], acc[m][n], 0, 0, 0);
  }

  const int rsub = (lane >> 4) << 2;
  #pragma unroll
  for (int m = 0; m < 4; ++m) {
    #pragma unroll
    for (int n = 0; n < 4; ++n) {
      const int col = bn * BN + wn * 64 + n * 16 + (lane & 15);
      #pragma unroll
      for (int j = 0; j < 4; ++j) {
        const int row = bm * BM + wm * 64 + m * 16 + rsub + j;
        out[(size_t)row * OUT_F + col] = acc[m][n][j];
      }
    }
  }
}

// ---------------------------------------------------------------------------
extern "C" void kernel_launch(void* const* d_in, const int* in_sizes, int n_in,
                              void* d_out, int out_size, void* d_ws, size_t ws_size,
                              hipStream_t stream) {
  (void)in_sizes; (void)n_in; (void)out_size;

  const float* x  = (const float*)d_in[0];
  const int*   qw = (const int*)d_in[1];
  const float* u  = (const float*)d_in[2];
  const float* vt = (const float*)d_in[3];
  float* out = (float*)d_out;

  unsigned short* w = (unsigned short*)d_ws;                   // 32 MB
  const size_t W_BYTES  = (size_t)OUT_F * IN_F * 2;
  const size_t XB_BYTES = (size_t)M_TOT * IN_F * 2;

  build_w<<<dim3(2048), dim3(256), 0, stream>>>(qw, u, vt, w);

  if (ws_size >= W_BYTES + XB_BYTES) {
    unsigned short* xb = w + (size_t)OUT_F * IN_F;
    convert_x<<<dim3(2048), dim3(256), 0, stream>>>(x, xb, M_TOT * IN_F / 8);
    gemm_256<<<dim3(512), dim3(512), 0, stream>>>(xb, w, out);
  } else {
    gemm_f32stage<<<dim3(2048), dim3(256), 0, stream>>>(x, w, out);
  }
}

// Round 7
// 391.891 us; speedup vs baseline: 1.4771x; 1.3061x over previous
//
#include <hip/hip_runtime.h>
#include <stdint.h>

// BitStackLinear. Device dtypes: x,u,vt = float32 (harness upcasts fp16),
// qweight = int32, out = float32.
// Pipeline: build_w (w bf16) ; convert_x (x bf16) ; 256x256 8-phase bf16 GEMM
// (T3+T4 counted vmcnt + T5 setprio + T2 chunk-XOR swizzle).

#define W_BITS 4
#define OUT_F  4096
#define IN_F   4096
#define K_RANK 16
#define M_TOT  8192
#define QW_PER_BIT (OUT_F * IN_F / 8)

typedef __attribute__((ext_vector_type(8))) short bf16x8;
typedef __attribute__((ext_vector_type(4))) float f32x4;

__device__ __forceinline__ unsigned short f2bf(float f) {
  union { float f; unsigned int u; } c; c.f = f;
  unsigned int r = c.u + 0x7fffu + ((c.u >> 16) & 1u);  // RNE
  return (unsigned short)(r >> 16);
}

// ---------------------------------------------------------------------------
// Kernel 0: X f32 -> bf16
// ---------------------------------------------------------------------------
__global__ __launch_bounds__(256) void convert_x(
    const float* __restrict__ X, unsigned short* __restrict__ Xb, int n8)
{
  const int stride = gridDim.x * blockDim.x;
  for (int i = blockIdx.x * blockDim.x + threadIdx.x; i < n8; i += stride) {
    const f32x4 a = *reinterpret_cast<const f32x4*>(X + (size_t)i * 8);
    const f32x4 b = *reinterpret_cast<const f32x4*>(X + (size_t)i * 8 + 4);
    unsigned short o8[8] = {f2bf(a[0]), f2bf(a[1]), f2bf(a[2]), f2bf(a[3]),
                            f2bf(b[0]), f2bf(b[1]), f2bf(b[2]), f2bf(b[3])};
    *reinterpret_cast<uint4*>(Xb + (size_t)i * 8) = *reinterpret_cast<const uint4*>(o8);
  }
}

// ---------------------------------------------------------------------------
// Kernel 1: w[o][i] = sum_bit sign * (u[bit] @ vt[bit])[o][i]; w bf16.
// ---------------------------------------------------------------------------
#define TO 4

__global__ __launch_bounds__(256) void build_w(
    const int*   __restrict__ qw,
    const float* __restrict__ u,
    const float* __restrict__ vt,
    unsigned short* __restrict__ w)
{
  const int tid = blockIdx.x * 256 + threadIdx.x;
  const int ig  = tid & 511;
  const int i0  = ig << 3;
  const int ob  = (tid >> 9) << 2;

  float acc[TO][8];
  #pragma unroll
  for (int t = 0; t < TO; ++t)
    #pragma unroll
    for (int ii = 0; ii < 8; ++ii) acc[t][ii] = 0.0f;

  #pragma unroll
  for (int bit = 0; bit < W_BITS; ++bit) {
    float lr[TO][8];
    #pragma unroll
    for (int t = 0; t < TO; ++t)
      #pragma unroll
      for (int ii = 0; ii < 8; ++ii) lr[t][ii] = 0.0f;

    const float* vbase = vt + (size_t)(bit * K_RANK) * IN_F + i0;
    const float* ubase = u + (size_t)(bit * OUT_F + ob) * K_RANK;

    #pragma unroll
    for (int k = 0; k < K_RANK; ++k) {
      const f32x4 v0 = *reinterpret_cast<const f32x4*>(vbase + (size_t)k * IN_F);
      const f32x4 v1 = *reinterpret_cast<const f32x4*>(vbase + (size_t)k * IN_F + 4);
      float vf[8] = {v0[0], v0[1], v0[2], v0[3], v1[0], v1[1], v1[2], v1[3]};
      #pragma unroll
      for (int t = 0; t < TO; ++t) {
        const float uk = ubase[t * K_RANK + k];
        #pragma unroll
        for (int ii = 0; ii < 8; ++ii) lr[t][ii] += uk * vf[ii];
      }
    }

    #pragma unroll
    for (int t = 0; t < TO; ++t) {
      const int q = qw[(size_t)bit * QW_PER_BIT + (size_t)(ob + t) * (IN_F / 8) + ig];
      #pragma unroll
      for (int ii = 0; ii < 8; ++ii)
        acc[t][ii] += ((q >> ii) & 1) ? lr[t][ii] : -lr[t][ii];
    }
  }

  #pragma unroll
  for (int t = 0; t < TO; ++t) {
    unsigned short o8[8];
    #pragma unroll
    for (int ii = 0; ii < 8; ++ii) o8[ii] = f2bf(acc[t][ii]);
    *reinterpret_cast<uint4*>(w + (size_t)(ob + t) * IN_F + i0) =
        *reinterpret_cast<const uint4*>(o8);
  }
}

// ---------------------------------------------------------------------------
// Kernel 2 (main): 256x256 tile, BK=64, 512 thr = 8 waves (2Mx4N), 8-phase,
// counted vmcnt(4), raw barriers, setprio. T2 chunk-XOR LDS swizzle:
//   physical_chunk = logical_chunk ^ (row & 7)   (chunk = 16B within 128B row)
// Applied as pre-swizzled GLOBAL source (LDS dest linear, per gload_lds rule)
// + swizzled ds_read offsets.
// ---------------------------------------------------------------------------
__device__ __forceinline__ void gll16(unsigned short* lds, const unsigned short* g) {
  __builtin_amdgcn_global_load_lds(
      (const __attribute__((address_space(1))) unsigned int*)g,
      (__attribute__((address_space(3))) unsigned int*)lds,
      16, 0, 0);
}

__global__ __launch_bounds__(512, 2) void gemm_256(
    const unsigned short* __restrict__ X,    // [M_TOT][IN_F] bf16
    const unsigned short* __restrict__ W,    // [OUT_F][IN_F] bf16
    float* __restrict__ out)                 // [M_TOT][OUT_F] f32
{
  __shared__ __align__(16) unsigned short Al[2][256][64];   // 64 KiB
  __shared__ __align__(16) unsigned short Bl[2][256][64];   // 64 KiB

  const int bid = blockIdx.x;                 // 512 blocks (32 x 16)
  const int swz = (bid & 7) * 64 + (bid >> 3);  // XCD-bijective (512%8==0)
  const int bm = swz >> 4;                    // 0..31
  const int bn = swz & 15;                    // 0..15

  const int tid  = threadIdx.x;
  const int lane = tid & 63;
  const int wid  = tid >> 6;     // 0..7
  const int wm   = wid >> 2;     // 0..1
  const int wn   = wid & 3;      // 0..3

  // staging: thread covers 16B; row sr, chunk (tid&7) PRE-SWIZZLED in source:
  // the chunk written at physical position (tid&7) is logical (tid&7)^(sr&7).
  const int sr = tid >> 3;                                  // 0..63
  const int sc = (((tid & 7) ^ (sr & 7)) << 3);             // shorts

  const unsigned short* Abase = X + (size_t)(bm * 256 + sr) * IN_F + sc;
  const unsigned short* Bbase = W + (size_t)(bn * 256 + sr) * IN_F + sc;
  unsigned short* Alt = &Al[0][0][0] + tid * 8;   // linear dest
  unsigned short* Blt = &Bl[0][0][0] + tid * 8;

  // fragment read coords (mfma_f32_16x16x32_bf16: lane l -> row l&15, k=(l>>4)*8..+7)
  // within-row chunk = ks*4 + hi, swizzled: ^ (row&7) = ^ (fr&7)
  const int fr  = lane & 15;
  const int sw0 = (((lane >> 4) ^ (fr & 7)) << 3);   // shorts; ks=1 adds ^32
  const int aRow = (wm * 16 + fr) * 64;              // + f*2048 + ((ks*32)^sw0)
  const int bRow = (wn * 16 + fr) * 64;              // + g*4096 + ((ks*32)^sw0)
  const unsigned short* Ar = &Al[0][0][0];
  const unsigned short* Br = &Bl[0][0][0];

  f32x4 acc[8][4];
  #pragma unroll
  for (int f = 0; f < 8; ++f)
    #pragma unroll
    for (int g = 0; g < 4; ++g)
      acc[f][g] = (f32x4){0.f, 0.f, 0.f, 0.f};

  // half-tile h: 0 = A rows 0-127, 1 = A rows 128-255, 2 = B-h0, 3 = B-h1
#define STAGE(buf, h, tn_) do {                                                        \
    const unsigned short* gs_ = ((h) < 2 ? Abase : Bbase)                              \
        + (size_t)(((h) & 1) * 128) * IN_F + (size_t)(tn_) * 64;                       \
    unsigned short* ld_ = ((h) < 2 ? Alt : Blt) + (buf) * 16384 + ((h) & 1) * 8192;    \
    gll16(ld_, gs_);                                                                   \
    gll16(ld_ + 4096, gs_ + (size_t)64 * IN_F);                                        \
  } while (0)

#define WAITBAR() do {                                                                 \
    asm volatile("s_waitcnt vmcnt(4)" ::: "memory");                                   \
    __builtin_amdgcn_s_barrier();                                                      \
    __builtin_amdgcn_sched_barrier(0);                                                 \
  } while (0)

#define PH_READ_A(mh_) {                                                               \
    _Pragma("unroll") for (int f = 0; f < 4; ++f)                                      \
      _Pragma("unroll") for (int ks = 0; ks < 2; ++ks)                                 \
        aF[f][ks] = *reinterpret_cast<const bf16x8*>(                                  \
            Ar + cbase + ((mh_) * 4 + f) * 2048 + aRow + ((ks * 32) ^ sw0)); }

#define PH_READ_B(nh_) {                                                               \
    _Pragma("unroll") for (int g = 0; g < 2; ++g)                                      \
      _Pragma("unroll") for (int ks = 0; ks < 2; ++ks)                                 \
        bF[g][ks] = *reinterpret_cast<const bf16x8*>(                                  \
            Br + cbase + ((nh_) * 2 + g) * 4096 + bRow + ((ks * 32) ^ sw0)); }

#define PH_MFMA(mh_, nh_) do {                                                         \
    __builtin_amdgcn_s_setprio(1);                                                     \
    _Pragma("unroll") for (int f = 0; f < 4; ++f)                                      \
      _Pragma("unroll") for (int g = 0; g < 2; ++g)                                    \
        _Pragma("unroll") for (int ks = 0; ks < 2; ++ks)                               \
          acc[(mh_) * 4 + f][(nh_) * 2 + g] = __builtin_amdgcn_mfma_f32_16x16x32_bf16( \
              aF[f][ks], bF[g][ks], acc[(mh_) * 4 + f][(nh_) * 2 + g], 0, 0, 0);       \
    __builtin_amdgcn_s_setprio(0);                                                     \
  } while (0)

  // prologue: stage tile 0 (A-h0, B-h0, A-h1, B-h1); vmcnt(4) -> first two
  // halves landed; steady-state invariant established.
  STAGE(0, 0, 0);
  STAGE(0, 2, 0);
  STAGE(0, 1, 0);
  STAGE(0, 3, 0);
  asm volatile("s_waitcnt vmcnt(4)" ::: "memory");
  __builtin_amdgcn_s_barrier();
  __builtin_amdgcn_sched_barrier(0);

  bf16x8 aF[4][2], bF[2][2];

  #pragma unroll 2
  for (int T = 0; T < 64; ++T) {
    const int cc = T & 1, oo = cc ^ 1;
    const int tn = (T < 63) ? T + 1 : 63;   // clamped prefetch (dup of 63, unread)
    const int cbase = cc * 16384;

    // phase 1: quadrant (0,0) — needs A-h0,B-h0 (landed 2 stage-groups ago)
    PH_READ_A(0); PH_READ_B(0);
    STAGE(oo, 0, tn);                 // next A-h0
    WAITBAR();
    PH_MFMA(0, 0);
    __builtin_amdgcn_s_barrier();

    // phase 2: quadrant (1,0) — needs A-h1 (completed by phase-1 vmcnt(4))
    PH_READ_A(1);
    STAGE(oo, 2, tn);                 // next B-h0
    WAITBAR();
    PH_MFMA(1, 0);
    __builtin_amdgcn_s_barrier();

    // phase 3: quadrant (1,1) — needs B-h1 (completed by phase-2 vmcnt(4))
    PH_READ_B(1);
    STAGE(oo, 1, tn);                 // next A-h1
    WAITBAR();
    PH_MFMA(1, 1);
    __builtin_amdgcn_s_barrier();

    // phase 4: quadrant (0,1) — re-reads A-h0 (long landed)
    PH_READ_A(0);
    STAGE(oo, 3, tn);                 // next B-h1
    WAITBAR();
    PH_MFMA(0, 1);
    __builtin_amdgcn_s_barrier();
  }

  asm volatile("s_waitcnt vmcnt(0)" ::: "memory");

  // epilogue: D mapping col = lane&15, row = (lane>>4)*4 + j [m89]
  const int rsub = (lane >> 4) << 2;
  #pragma unroll
  for (int f = 0; f < 8; ++f) {
    const int row = bm * 256 + (f * 2 + wm) * 16 + rsub;
    #pragma unroll
    for (int g = 0; g < 4; ++g) {
      const int col = bn * 256 + (g * 4 + wn) * 16 + (lane & 15);
      float* op = out + (size_t)row * OUT_F + col;
      #pragma unroll
      for (int j = 0; j < 4; ++j) op[(size_t)j * OUT_F] = acc[f][g][j];
    }
  }
#undef STAGE
#undef WAITBAR
#undef PH_READ_A
#undef PH_READ_B
#undef PH_MFMA
}

// ---------------------------------------------------------------------------
// Fallback GEMM (round-4, passing): A f32 reg-staged+converted. ws < 96MB only.
// ---------------------------------------------------------------------------
#define BM 128
#define BN 128
#define BK 32

__device__ __forceinline__ uint4 cvt8(f32x4 a, f32x4 b) {
  unsigned short o8[8] = {f2bf(a[0]), f2bf(a[1]), f2bf(a[2]), f2bf(a[3]),
                          f2bf(b[0]), f2bf(b[1]), f2bf(b[2]), f2bf(b[3])};
  return *reinterpret_cast<const uint4*>(o8);
}

__global__ __launch_bounds__(256) void gemm_f32stage(
    const float* __restrict__ X,
    const unsigned short* __restrict__ W,
    float* __restrict__ out)
{
  __shared__ __align__(16) unsigned short As[BM * BK];
  __shared__ __align__(16) unsigned short Bs[BN * BK];

  const int nbn = OUT_F / BN;
  const int cpx = (M_TOT / BM) * nbn / 8;
  const int bid = blockIdx.x;
  const int swz = (bid & 7) * cpx + (bid >> 3);
  const int bm = swz / nbn;
  const int bn = swz % nbn;

  const int tid  = threadIdx.x;
  const int lane = tid & 63;
  const int wid  = tid >> 6;
  const int wm   = wid >> 1;
  const int wn   = wid & 1;
  const int srow = tid >> 2;
  const int scol = (tid & 3) << 3;

  const float*          Ag = X + (size_t)(bm * BM + srow) * IN_F + scol;
  const unsigned short* Bg = W + (size_t)(bn * BN + srow) * IN_F + scol;

  const int fr = lane & 15;
  const int fk = (lane >> 4) << 3;

  f32x4 acc[4][4];
  #pragma unroll
  for (int m = 0; m < 4; ++m)
    #pragma unroll
    for (int n = 0; n < 4; ++n)
      acc[m][n] = (f32x4){0.f, 0.f, 0.f, 0.f};

  for (int k0 = 0; k0 < IN_F; k0 += BK) {
    const f32x4 a0a = *reinterpret_cast<const f32x4*>(Ag + k0);
    const f32x4 a0b = *reinterpret_cast<const f32x4*>(Ag + k0 + 4);
    const f32x4 a1a = *reinterpret_cast<const f32x4*>(Ag + (size_t)64 * IN_F + k0);
    const f32x4 a1b = *reinterpret_cast<const f32x4*>(Ag + (size_t)64 * IN_F + k0 + 4);
    const uint4 b0  = *reinterpret_cast<const uint4*>(Bg + k0);
    const uint4 b1  = *reinterpret_cast<const uint4*>(Bg + (size_t)64 * IN_F + k0);

    __syncthreads();
    *reinterpret_cast<uint4*>(As + tid * 8)        = cvt8(a0a, a0b);
    *reinterpret_cast<uint4*>(As + 2048 + tid * 8) = cvt8(a1a, a1b);
    *reinterpret_cast<uint4*>(Bs + tid * 8)        = b0;
    *reinterpret_cast<uint4*>(Bs + 2048 + tid * 8) = b1;
    __syncthreads();

    bf16x8 af[4], bfv[4];
    #pragma unroll
    for (int m = 0; m < 4; ++m)
      af[m] = *reinterpret_cast<const bf16x8*>(&As[(wm * 64 + m * 16 + fr) * BK + fk]);
    #pragma unroll
    for (int n = 0; n < 4; ++n)
      bfv[n] = *reinterpret_cast<const bf16x8*>(&Bs[(wn * 64 + n * 16 + fr) * BK + fk]);

    #pragma unroll
    for (int m = 0; m < 4; ++m)
      #pragma unroll
      for (int n = 0; n < 4; ++n)
        acc[m][n] = __builtin_amdgcn_mfma_f32_16x16x32_bf16(af[m], bfv[n], acc[m][n], 0, 0, 0);
  }

  const int rsub = (lane >> 4) << 2;
  #pragma unroll
  for (int m = 0; m < 4; ++m) {
    #pragma unroll
    for (int n = 0; n < 4; ++n) {
      const int col = bn * BN + wn * 64 + n * 16 + (lane & 15);
      #pragma unroll
      for (int j = 0; j < 4; ++j) {
        const int row = bm * BM + wm * 64 + m * 16 + rsub + j;
        out[(size_t)row * OUT_F + col] = acc[m][n][j];
      }
    }
  }
}

// ---------------------------------------------------------------------------
extern "C" void kernel_launch(void* const* d_in, const int* in_sizes, int n_in,
                              void* d_out, int out_size, void* d_ws, size_t ws_size,
                              hipStream_t stream) {
  (void)in_sizes; (void)n_in; (void)out_size;

  const float* x  = (const float*)d_in[0];
  const int*   qw = (const int*)d_in[1];
  const float* u  = (const float*)d_in[2];
  const float* vt = (const float*)d_in[3];
  float* out = (float*)d_out;

  unsigned short* w = (unsigned short*)d_ws;                   // 32 MB
  const size_t W_BYTES  = (size_t)OUT_F * IN_F * 2;
  const size_t XB_BYTES = (size_t)M_TOT * IN_F * 2;

  build_w<<<dim3(2048), dim3(256), 0, stream>>>(qw, u, vt, w);

  if (ws_size >= W_BYTES + XB_BYTES) {
    unsigned short* xb = w + (size_t)OUT_F * IN_F;
    convert_x<<<dim3(2048), dim3(256), 0, stream>>>(x, xb, M_TOT * IN_F / 8);
    gemm_256<<<dim3(512), dim3(512), 0, stream>>>(xb, w, out);
  } else {
    gemm_f32stage<<<dim3(2048), dim3(256), 0, stream>>>(x, w, out);
  }
}

// Round 8
// 365.731 us; speedup vs baseline: 1.5828x; 1.0715x over previous
//
#include <hip/hip_runtime.h>
#include <stdint.h>

// BitStackLinear. Device dtypes: x,u,vt = float32 (harness upcasts fp16),
// qweight = int32, out = float32.
// Pipeline: build_w (w bf16) ; convert_x (x bf16) ; 256x256 8-phase bf16 GEMM
// (T2 chunk-XOR swizzle + T3/T4 counted vmcnt + T5 setprio).
// Round 8: Gray-code quadrant order (0,0)->(0,1)->(1,1)->(1,0) with B0 carried
// in registers -> 24 ds_read_b128/K-tile instead of 32 (A-h0 re-read removed).

#define W_BITS 4
#define OUT_F  4096
#define IN_F   4096
#define K_RANK 16
#define M_TOT  8192
#define QW_PER_BIT (OUT_F * IN_F / 8)

typedef __attribute__((ext_vector_type(8))) short bf16x8;
typedef __attribute__((ext_vector_type(4))) float f32x4;

__device__ __forceinline__ unsigned short f2bf(float f) {
  union { float f; unsigned int u; } c; c.f = f;
  unsigned int r = c.u + 0x7fffu + ((c.u >> 16) & 1u);  // RNE
  return (unsigned short)(r >> 16);
}

// ---------------------------------------------------------------------------
// Kernel 0: X f32 -> bf16
// ---------------------------------------------------------------------------
__global__ __launch_bounds__(256) void convert_x(
    const float* __restrict__ X, unsigned short* __restrict__ Xb, int n8)
{
  const int stride = gridDim.x * blockDim.x;
  for (int i = blockIdx.x * blockDim.x + threadIdx.x; i < n8; i += stride) {
    const f32x4 a = *reinterpret_cast<const f32x4*>(X + (size_t)i * 8);
    const f32x4 b = *reinterpret_cast<const f32x4*>(X + (size_t)i * 8 + 4);
    unsigned short o8[8] = {f2bf(a[0]), f2bf(a[1]), f2bf(a[2]), f2bf(a[3]),
                            f2bf(b[0]), f2bf(b[1]), f2bf(b[2]), f2bf(b[3])};
    *reinterpret_cast<uint4*>(Xb + (size_t)i * 8) = *reinterpret_cast<const uint4*>(o8);
  }
}

// ---------------------------------------------------------------------------
// Kernel 1: w[o][i] = sum_bit sign * (u[bit] @ vt[bit])[o][i]; w bf16.
// ---------------------------------------------------------------------------
#define TO 4

__global__ __launch_bounds__(256) void build_w(
    const int*   __restrict__ qw,
    const float* __restrict__ u,
    const float* __restrict__ vt,
    unsigned short* __restrict__ w)
{
  const int tid = blockIdx.x * 256 + threadIdx.x;
  const int ig  = tid & 511;
  const int i0  = ig << 3;
  const int ob  = (tid >> 9) << 2;

  float acc[TO][8];
  #pragma unroll
  for (int t = 0; t < TO; ++t)
    #pragma unroll
    for (int ii = 0; ii < 8; ++ii) acc[t][ii] = 0.0f;

  #pragma unroll
  for (int bit = 0; bit < W_BITS; ++bit) {
    float lr[TO][8];
    #pragma unroll
    for (int t = 0; t < TO; ++t)
      #pragma unroll
      for (int ii = 0; ii < 8; ++ii) lr[t][ii] = 0.0f;

    const float* vbase = vt + (size_t)(bit * K_RANK) * IN_F + i0;
    const float* ubase = u + (size_t)(bit * OUT_F + ob) * K_RANK;

    #pragma unroll
    for (int k = 0; k < K_RANK; ++k) {
      const f32x4 v0 = *reinterpret_cast<const f32x4*>(vbase + (size_t)k * IN_F);
      const f32x4 v1 = *reinterpret_cast<const f32x4*>(vbase + (size_t)k * IN_F + 4);
      float vf[8] = {v0[0], v0[1], v0[2], v0[3], v1[0], v1[1], v1[2], v1[3]};
      #pragma unroll
      for (int t = 0; t < TO; ++t) {
        const float uk = ubase[t * K_RANK + k];
        #pragma unroll
        for (int ii = 0; ii < 8; ++ii) lr[t][ii] += uk * vf[ii];
      }
    }

    #pragma unroll
    for (int t = 0; t < TO; ++t) {
      const int q = qw[(size_t)bit * QW_PER_BIT + (size_t)(ob + t) * (IN_F / 8) + ig];
      #pragma unroll
      for (int ii = 0; ii < 8; ++ii)
        acc[t][ii] += ((q >> ii) & 1) ? lr[t][ii] : -lr[t][ii];
    }
  }

  #pragma unroll
  for (int t = 0; t < TO; ++t) {
    unsigned short o8[8];
    #pragma unroll
    for (int ii = 0; ii < 8; ++ii) o8[ii] = f2bf(acc[t][ii]);
    *reinterpret_cast<uint4*>(w + (size_t)(ob + t) * IN_F + i0) =
        *reinterpret_cast<const uint4*>(o8);
  }
}

// ---------------------------------------------------------------------------
// Kernel 2 (main): 256x256 tile, BK=64, 512 thr = 8 waves (2Mx4N), 4-phase
// Gray-code schedule, counted vmcnt(4), raw barriers, setprio, chunk-XOR LDS
// swizzle (pre-swizzled global source + swizzled ds_read, linear LDS dest).
// Reads/K-tile/wave: ph1 A0(8)+B0(4), ph2 B1(4), ph3 A1(8), ph4 none = 24.
// Stage slots:       ph1 A0',      ph2 B0',   ph3 B1',   ph4 A1'.
// Deadlines (uniform vmcnt(4), guarantee = prev WAITBAR covers stages <= p-2):
//   A0'/B0' read ph1 (staged ph1/ph2 prev iter, 4/3 groups old)  OK
//   B1' read ph2 (staged ph3 prev, 3 old) OK ; A1' read ph3 (ph4 prev, 3) OK
// ---------------------------------------------------------------------------
__device__ __forceinline__ void gll16(unsigned short* lds, const unsigned short* g) {
  __builtin_amdgcn_global_load_lds(
      (const __attribute__((address_space(1))) unsigned int*)g,
      (__attribute__((address_space(3))) unsigned int*)lds,
      16, 0, 0);
}

__global__ __launch_bounds__(512, 2) void gemm_256(
    const unsigned short* __restrict__ X,    // [M_TOT][IN_F] bf16
    const unsigned short* __restrict__ W,    // [OUT_F][IN_F] bf16
    float* __restrict__ out)                 // [M_TOT][OUT_F] f32
{
  __shared__ __align__(16) unsigned short Al[2][256][64];   // 64 KiB
  __shared__ __align__(16) unsigned short Bl[2][256][64];   // 64 KiB

  const int bid = blockIdx.x;                 // 512 blocks (32 x 16)
  const int swz = (bid & 7) * 64 + (bid >> 3);  // XCD-bijective (512%8==0)
  const int bm = swz >> 4;                    // 0..31
  const int bn = swz & 15;                    // 0..15

  const int tid  = threadIdx.x;
  const int lane = tid & 63;
  const int wid  = tid >> 6;     // 0..7
  const int wm   = wid >> 2;     // 0..1
  const int wn   = wid & 3;      // 0..3

  // staging: row sr, physical chunk tid&7 holds logical chunk (tid&7)^(sr&7)
  const int sr = tid >> 3;                                  // 0..63
  const int sc = (((tid & 7) ^ (sr & 7)) << 3);             // shorts

  const unsigned short* Abase = X + (size_t)(bm * 256 + sr) * IN_F + sc;
  const unsigned short* Bbase = W + (size_t)(bn * 256 + sr) * IN_F + sc;
  unsigned short* Alt = &Al[0][0][0] + tid * 8;   // linear dest
  unsigned short* Blt = &Bl[0][0][0] + tid * 8;

  // fragment reads (mfma_f32_16x16x32_bf16: lane l -> row l&15, k=(l>>4)*8..+7)
  // within-row chunk = ks*4 + (lane>>4), swizzled by ^(row&7)
  const int fr  = lane & 15;
  const int sw0 = (((lane >> 4) ^ (fr & 7)) << 3);   // shorts; ks=1 adds ^32
  const int aRow = (wm * 16 + fr) * 64;              // + f*2048 + ((ks*32)^sw0)
  const int bRow = (wn * 16 + fr) * 64;              // + g*4096 + ((ks*32)^sw0)
  const unsigned short* Ar = &Al[0][0][0];
  const unsigned short* Br = &Bl[0][0][0];

  f32x4 acc[8][4];
  #pragma unroll
  for (int f = 0; f < 8; ++f)
    #pragma unroll
    for (int g = 0; g < 4; ++g)
      acc[f][g] = (f32x4){0.f, 0.f, 0.f, 0.f};

  // half-tile h: 0 = A rows 0-127, 1 = A rows 128-255, 2 = B-h0, 3 = B-h1
#define STAGE(buf, h, tn_) do {                                                        \
    const unsigned short* gs_ = ((h) < 2 ? Abase : Bbase)                              \
        + (size_t)(((h) & 1) * 128) * IN_F + (size_t)(tn_) * 64;                       \
    unsigned short* ld_ = ((h) < 2 ? Alt : Blt) + (buf) * 16384 + ((h) & 1) * 8192;    \
    gll16(ld_, gs_);                                                                   \
    gll16(ld_ + 4096, gs_ + (size_t)64 * IN_F);                                        \
  } while (0)

#define WAITBAR() do {                                                                 \
    asm volatile("s_waitcnt vmcnt(4)" ::: "memory");                                   \
    __builtin_amdgcn_s_barrier();                                                      \
    __builtin_amdgcn_sched_barrier(0);                                                 \
  } while (0)

#define PH_READ_A(mh_) {                                                               \
    _Pragma("unroll") for (int f = 0; f < 4; ++f)                                      \
      _Pragma("unroll") for (int ks = 0; ks < 2; ++ks)                                 \
        aF[f][ks] = *reinterpret_cast<const bf16x8*>(                                  \
            Ar + cbase + ((mh_) * 4 + f) * 2048 + aRow + ((ks * 32) ^ sw0)); }

#define PH_READ_B(nh_, dst_) {                                                         \
    _Pragma("unroll") for (int g = 0; g < 2; ++g)                                      \
      _Pragma("unroll") for (int ks = 0; ks < 2; ++ks)                                 \
        dst_[g][ks] = *reinterpret_cast<const bf16x8*>(                                \
            Br + cbase + ((nh_) * 2 + g) * 4096 + bRow + ((ks * 32) ^ sw0)); }

#define PH_MFMA(mh_, nh_, bsrc_) do {                                                  \
    __builtin_amdgcn_s_setprio(1);                                                     \
    _Pragma("unroll") for (int f = 0; f < 4; ++f)                                      \
      _Pragma("unroll") for (int g = 0; g < 2; ++g)                                    \
        _Pragma("unroll") for (int ks = 0; ks < 2; ++ks)                               \
          acc[(mh_) * 4 + f][(nh_) * 2 + g] = __builtin_amdgcn_mfma_f32_16x16x32_bf16( \
              aF[f][ks], bsrc_[g][ks], acc[(mh_) * 4 + f][(nh_) * 2 + g], 0, 0, 0);    \
    __builtin_amdgcn_s_setprio(0);                                                     \
  } while (0)

  // prologue: stage tile 0 in deadline order A0,B0,B1,A1; vmcnt(4) -> A0,B0
  // landed; iter-0 ledger then matches steady state.
  STAGE(0, 0, 0);
  STAGE(0, 2, 0);
  STAGE(0, 3, 0);
  STAGE(0, 1, 0);
  asm volatile("s_waitcnt vmcnt(4)" ::: "memory");
  __builtin_amdgcn_s_barrier();
  __builtin_amdgcn_sched_barrier(0);

  bf16x8 aF[4][2], bF0[2][2], bF1[2][2];

  #pragma unroll 2
  for (int T = 0; T < 64; ++T) {
    const int cc = T & 1, oo = cc ^ 1;
    const int tn = (T < 63) ? T + 1 : 63;   // clamped prefetch (dup of 63, unread)
    const int cbase = cc * 16384;

    // phase 1: quadrant (0,0) — A0, B0 (B0 kept in regs through phase 4)
    PH_READ_A(0); PH_READ_B(0, bF0);
    STAGE(oo, 0, tn);                 // next A0
    WAITBAR();
    PH_MFMA(0, 0, bF0);
    __builtin_amdgcn_s_barrier();

    // phase 2: quadrant (0,1) — reuse aF(A0), read B1
    PH_READ_B(1, bF1);
    STAGE(oo, 2, tn);                 // next B0
    WAITBAR();
    PH_MFMA(0, 1, bF1);
    __builtin_amdgcn_s_barrier();

    // phase 3: quadrant (1,1) — read A1 (overwrites aF), reuse bF1
    PH_READ_A(1);
    STAGE(oo, 3, tn);                 // next B1
    WAITBAR();
    PH_MFMA(1, 1, bF1);
    __builtin_amdgcn_s_barrier();

    // phase 4: quadrant (1,0) — no reads: reuse aF(A1) and bF0(B0)
    STAGE(oo, 1, tn);                 // next A1
    WAITBAR();
    PH_MFMA(1, 0, bF0);
    __builtin_amdgcn_s_barrier();
  }

  asm volatile("s_waitcnt vmcnt(0)" ::: "memory");

  // epilogue: D mapping col = lane&15, row = (lane>>4)*4 + j [m89]
  const int rsub = (lane >> 4) << 2;
  #pragma unroll
  for (int f = 0; f < 8; ++f) {
    const int row = bm * 256 + (f * 2 + wm) * 16 + rsub;
    #pragma unroll
    for (int g = 0; g < 4; ++g) {
      const int col = bn * 256 + (g * 4 + wn) * 16 + (lane & 15);
      float* op = out + (size_t)row * OUT_F + col;
      #pragma unroll
      for (int j = 0; j < 4; ++j) op[(size_t)j * OUT_F] = acc[f][g][j];
    }
  }
#undef STAGE
#undef WAITBAR
#undef PH_READ_A
#undef PH_READ_B
#undef PH_MFMA
}

// ---------------------------------------------------------------------------
// Fallback GEMM (round-4, passing): A f32 reg-staged+converted. ws < 96MB only.
// ---------------------------------------------------------------------------
#define BM 128
#define BN 128
#define BK 32

__device__ __forceinline__ uint4 cvt8(f32x4 a, f32x4 b) {
  unsigned short o8[8] = {f2bf(a[0]), f2bf(a[1]), f2bf(a[2]), f2bf(a[3]),
                          f2bf(b[0]), f2bf(b[1]), f2bf(b[2]), f2bf(b[3])};
  return *reinterpret_cast<const uint4*>(o8);
}

__global__ __launch_bounds__(256) void gemm_f32stage(
    const float* __restrict__ X,
    const unsigned short* __restrict__ W,
    float* __restrict__ out)
{
  __shared__ __align__(16) unsigned short As[BM * BK];
  __shared__ __align__(16) unsigned short Bs[BN * BK];

  const int nbn = OUT_F / BN;
  const int cpx = (M_TOT / BM) * nbn / 8;
  const int bid = blockIdx.x;
  const int swz = (bid & 7) * cpx + (bid >> 3);
  const int bm = swz / nbn;
  const int bn = swz % nbn;

  const int tid  = threadIdx.x;
  const int lane = tid & 63;
  const int wid  = tid >> 6;
  const int wm   = wid >> 1;
  const int wn   = wid & 1;
  const int srow = tid >> 2;
  const int scol = (tid & 3) << 3;

  const float*          Ag = X + (size_t)(bm * BM + srow) * IN_F + scol;
  const unsigned short* Bg = W + (size_t)(bn * BN + srow) * IN_F + scol;

  const int fr = lane & 15;
  const int fk = (lane >> 4) << 3;

  f32x4 acc[4][4];
  #pragma unroll
  for (int m = 0; m < 4; ++m)
    #pragma unroll
    for (int n = 0; n < 4; ++n)
      acc[m][n] = (f32x4){0.f, 0.f, 0.f, 0.f};

  for (int k0 = 0; k0 < IN_F; k0 += BK) {
    const f32x4 a0a = *reinterpret_cast<const f32x4*>(Ag + k0);
    const f32x4 a0b = *reinterpret_cast<const f32x4*>(Ag + k0 + 4);
    const f32x4 a1a = *reinterpret_cast<const f32x4*>(Ag + (size_t)64 * IN_F + k0);
    const f32x4 a1b = *reinterpret_cast<const f32x4*>(Ag + (size_t)64 * IN_F + k0 + 4);
    const uint4 b0  = *reinterpret_cast<const uint4*>(Bg + k0);
    const uint4 b1  = *reinterpret_cast<const uint4*>(Bg + (size_t)64 * IN_F + k0);

    __syncthreads();
    *reinterpret_cast<uint4*>(As + tid * 8)        = cvt8(a0a, a0b);
    *reinterpret_cast<uint4*>(As + 2048 + tid * 8) = cvt8(a1a, a1b);
    *reinterpret_cast<uint4*>(Bs + tid * 8)        = b0;
    *reinterpret_cast<uint4*>(Bs + 2048 + tid * 8) = b1;
    __syncthreads();

    bf16x8 af[4], bfv[4];
    #pragma unroll
    for (int m = 0; m < 4; ++m)
      af[m] = *reinterpret_cast<const bf16x8*>(&As[(wm * 64 + m * 16 + fr) * BK + fk]);
    #pragma unroll
    for (int n = 0; n < 4; ++n)
      bfv[n] = *reinterpret_cast<const bf16x8*>(&Bs[(wn * 64 + n * 16 + fr) * BK + fk]);

    #pragma unroll
    for (int m = 0; m < 4; ++m)
      #pragma unroll
      for (int n = 0; n < 4; ++n)
        acc[m][n] = __builtin_amdgcn_mfma_f32_16x16x32_bf16(af[m], bfv[n], acc[m][n], 0, 0, 0);
  }

  const int rsub = (lane >> 4) << 2;
  #pragma unroll
  for (int m = 0; m < 4; ++m) {
    #pragma unroll
    for (int n = 0; n < 4; ++n) {
      const int col = bn * BN + wn * 64 + n * 16 + (lane & 15);
      #pragma unroll
      for (int j = 0; j < 4; ++j) {
        const int row = bm * BM + wm * 64 + m * 16 + rsub + j;
        out[(size_t)row * OUT_F + col] = acc[m][n][j];
      }
    }
  }
}

// ---------------------------------------------------------------------------
extern "C" void kernel_launch(void* const* d_in, const int* in_sizes, int n_in,
                              void* d_out, int out_size, void* d_ws, size_t ws_size,
                              hipStream_t stream) {
  (void)in_sizes; (void)n_in; (void)out_size;

  const float* x  = (const float*)d_in[0];
  const int*   qw = (const int*)d_in[1];
  const float* u  = (const float*)d_in[2];
  const float* vt = (const float*)d_in[3];
  float* out = (float*)d_out;

  unsigned short* w = (unsigned short*)d_ws;                   // 32 MB
  const size_t W_BYTES  = (size_t)OUT_F * IN_F * 2;
  const size_t XB_BYTES = (size_t)M_TOT * IN_F * 2;

  build_w<<<dim3(2048), dim3(256), 0, stream>>>(qw, u, vt, w);

  if (ws_size >= W_BYTES + XB_BYTES) {
    unsigned short* xb = w + (size_t)OUT_F * IN_F;
    convert_x<<<dim3(2048), dim3(256), 0, stream>>>(x, xb, M_TOT * IN_F / 8);
    gemm_256<<<dim3(512), dim3(512), 0, stream>>>(xb, w, out);
  } else {
    gemm_f32stage<<<dim3(2048), dim3(256), 0, stream>>>(x, w, out);
  }
}